// Round 8
// baseline (332.453 us; speedup 1.0000x reference)
//
#include <hip/hip_runtime.h>
#include <stdint.h>

typedef __attribute__((ext_vector_type(8))) short short8;
typedef __attribute__((ext_vector_type(4))) float floatx4;

// ---------- helpers ----------
__device__ __forceinline__ float bf16_to_f(uint16_t u) {
    union { uint32_t i; float f; } v; v.i = ((uint32_t)u) << 16; return v.f;
}
__device__ __forceinline__ uint16_t f_to_bf16(float f) {
    union { uint32_t i; float f; } v; v.f = f;
    uint32_t u = v.i;
    u += 0x7FFFu + ((u >> 16) & 1u);   // round-to-nearest-even
    return (uint16_t)(u >> 16);
}
__device__ __forceinline__ void gload16(const void* g, void* l) {
    __builtin_amdgcn_global_load_lds(
        (const __attribute__((address_space(1))) void*)g,
        (__attribute__((address_space(3))) void*)l, 16, 0, 0);
}
__device__ __forceinline__ float rcpf(float x) { return __builtin_amdgcn_rcpf(x); }

// LDS-only barrier: waits own LDS ops, does NOT drain vmcnt.
__device__ __forceinline__ void bar_lds() {
    asm volatile("s_waitcnt lgkmcnt(0)" ::: "memory");
    __builtin_amdgcn_s_barrier();
    asm volatile("" ::: "memory");
}

#define B_  32
#define T_  512
#define CF_ 2048
#define H_  128
#define G4_ 512   // 4*H
#define BT_ 16384 // B_*T_
#define LOG2E 1.4426950408889634f

// =====================================================================
// k_cvt_all: weights fp32 -> bf16. W_fc1 additionally PRE-SWIZZLED into
// exact MFMA a-frag order: element (d,k) -> Wswz[((kc*8+mf)*64+lk*16+lm)*8+e]
// with kc=k>>5, lk=(k>>3)&3, e=k&7, mf=d>>4, lm=d&15. A wave's a-frag
// load in k_fc1w is then 64 lanes x 16B CONTIGUOUS (1 KB per instr) —
// eliminates the 64-cache-line strided W reads of all prior variants.
// =====================================================================
__global__ __launch_bounds__(256) void k_cvt_all(
        const float* __restrict__ Wfc, const float* __restrict__ Wih_f,
        const float* __restrict__ Wih_b, const float* __restrict__ Whh_f,
        const float* __restrict__ Whh_b, const float* __restrict__ Wout,
        uint16_t* __restrict__ WswzB, uint16_t* __restrict__ WihB,
        uint16_t* __restrict__ WhhB, uint16_t* __restrict__ WoutB) {
    const int blk = blockIdx.x;
    if (blk < 256) {
        const int i = blk * 1024 + threadIdx.x * 4;
        const int d = i >> 11, k = i & 2047;
        float4 v = *(const float4*)&Wfc[i];
        ushort4 o;
        o.x = f_to_bf16(v.x); o.y = f_to_bf16(v.y);
        o.z = f_to_bf16(v.z); o.w = f_to_bf16(v.w);
        const int kc = k >> 5, lk = (k >> 3) & 3, e = k & 7;
        const int mf = d >> 4, lm = d & 15;
        *(ushort4*)&WswzB[(size_t)(((kc * 8 + mf) * 64 + lk * 16 + lm) * 8 + e)] = o;
        return;
    }
    const float* s; uint16_t* d; int off;
    if (blk < 320)      { s = Wih_f; d = WihB;          off = blk - 256; }
    else if (blk < 384) { s = Wih_b; d = WihB + 65536;  off = blk - 320; }
    else if (blk < 448) { s = Whh_f; d = WhhB;          off = blk - 384; }
    else if (blk < 512) { s = Whh_b; d = WhhB + 65536;  off = blk - 448; }
    else                { s = Wout;  d = WoutB;         off = blk - 512; }
    const int i = off * 1024 + threadIdx.x * 4;
    float4 v = *(const float4*)&s[i];
    ushort4 o;
    o.x = f_to_bf16(v.x); o.y = f_to_bf16(v.y);
    o.z = f_to_bf16(v.z); o.w = f_to_bf16(v.w);
    *(ushort4*)&d[i] = o;
}

// =====================================================================
// k_fc1w: BARRIER-FREE, LDS-FREE fc1 GEMM core.
// Wave = (t-tile of 16 bt, k-split kc of K=512, all 128 d). Grid 1024
// blocks x 256 thr = 4096 waves = 4 blocks/CU = 16 waves/CU, every wave
// issuing loads continuously (no __syncthreads anywhere).
// Per k-step (K=32): 8 scalar x dwords (16-lane 64B runs) -> bf16 b-frag
// in registers; 8 contiguous 16B a-frag loads from pre-swizzled Wswz;
// 8 MFMA. fp32 partials -> Hpart[kc] (k_hsum reduces, same as R7).
// =====================================================================
__global__ __launch_bounds__(256) void k_fc1w(const float* __restrict__ x,
                                              const uint16_t* __restrict__ Wswz,
                                              float* __restrict__ Hpart) {
    const int tid = threadIdx.x, w = tid >> 6, l = tid & 63;
    const int lm = l & 15, lk = l >> 4;
    const int bt0 = blockIdx.x * 16;
    const int bb = bt0 >> 9, t0 = bt0 & 511;
    const int kc4 = w;                       // k-split 0..3 (K=512 each)
    const float* xb = x + ((size_t)bb * CF_ + kc4 * 512) * T_ + t0 + lm;

    floatx4 acc[8] = {};                     // acc[mf], mf = d/16
    #pragma unroll 2
    for (int s = 0; s < 16; ++s) {
        const int kk = s * 32;
        // b-frag: x[k0+lk*8+j][t0+lm], j=0..7 (each instr: 4x 64B runs)
        float xv[8];
        #pragma unroll
        for (int j = 0; j < 8; ++j)
            xv[j] = xb[(size_t)(kk + lk * 8 + j) * T_];
        short8 bfr;
        #pragma unroll
        for (int j = 0; j < 8; ++j)
            bfr[j] = (short)f_to_bf16(xv[j]);
        // a-frags: contiguous 1KB per instr from swizzled W
        const uint16_t* wp = Wswz + ((size_t)(kc4 * 16 + s) * 8 * 64 + l) * 8;
        #pragma unroll
        for (int mf = 0; mf < 8; ++mf) {
            short8 a = *(const short8*)(wp + mf * 512);
            acc[mf] = __builtin_amdgcn_mfma_f32_16x16x32_bf16(a, bfr, acc[mf], 0, 0, 0);
        }
    }
    // epilogue: fp32 partials, C/D layout row d = mf*16+lk*4+r, col bt0+lm
    float* Hp = Hpart + (size_t)kc4 * H_ * BT_;
    #pragma unroll
    for (int mf = 0; mf < 8; ++mf) {
        const int d0 = mf * 16 + lk * 4;
        #pragma unroll
        for (int r = 0; r < 4; ++r)
            Hp[(size_t)(d0 + r) * BT_ + bt0 + lm] = acc[mf][r];
    }
}

// =====================================================================
// k_hsum: Hfc_cm = bf16(sum_kc Hpart + bias), chunk-major output
// [c=d>>3][bt][e=d&7] — the B-layout k_xproj's gload_lds needs.
// =====================================================================
__global__ __launch_bounds__(256) void k_hsum(const float* __restrict__ Hpart,
                                              const float* __restrict__ bfc,
                                              uint16_t* __restrict__ Hcm) {
    const int d = blockIdx.y, bt = blockIdx.x * 1024 + threadIdx.x * 4;
    const float b = bfc[d];
    float4 s = *(const float4*)&Hpart[(size_t)d * BT_ + bt];
    #pragma unroll
    for (int kc = 1; kc < 4; ++kc) {
        const float4 v = *(const float4*)&Hpart[(size_t)kc * H_ * BT_ + (size_t)d * BT_ + bt];
        s.x += v.x; s.y += v.y; s.z += v.z; s.w += v.w;
    }
    uint16_t* o = Hcm + ((size_t)(d >> 3) * BT_ + bt) * 8 + (d & 7);
    o[0]  = f_to_bf16(s.x + b);
    o[8]  = f_to_bf16(s.y + b);
    o[16] = f_to_bf16(s.z + b);
    o[24] = f_to_bf16(s.w + b);
}

// =====================================================================
// k_xproj: Xp = Wih_cat[1024 x 128] @ Hfc[128 x 16384]. (R7, verified)
// =====================================================================
__global__ __launch_bounds__(256) void k_xproj(const uint16_t* __restrict__ Hcm,
                                               const uint16_t* __restrict__ WihB,
                                               const float* __restrict__ b_f,
                                               const float* __restrict__ b_b,
                                               uint16_t* __restrict__ Xp) {
    __shared__ __align__(16) uint16_t As[64 * 136];
    __shared__ __align__(16) uint16_t Bs[16 * 66 * 8];
    const int bt0 = blockIdx.x * 64, gy = blockIdx.y;
    const int dir = gy >> 3;
    const int gl0 = gy * 64 - dir * 512;
    const int tid = threadIdx.x, w = tid >> 6, l = tid & 63;
    const int lm = l & 15, lk = l >> 4;

    #pragma unroll
    for (int j = 0; j < 4; ++j) {
        const int c = w * 4 + j;
        gload16(Hcm + ((size_t)c * BT_ + bt0 + l) * 8, Bs + (c * 66 + l) * 8);
    }
    {
        const int r = tid >> 2, c4 = tid & 3;
        const uint16_t* src = WihB + (size_t)(gy * 64 + r) * H_ + c4 * 32;
        short8 v0 = *(const short8*)(src);
        short8 v1 = *(const short8*)(src + 8);
        short8 v2 = *(const short8*)(src + 16);
        short8 v3 = *(const short8*)(src + 24);
        uint16_t* dst = &As[r * 136 + c4 * 32];
        *(short8*)(dst)      = v0;
        *(short8*)(dst + 8)  = v1;
        *(short8*)(dst + 16) = v2;
        *(short8*)(dst + 24) = v3;
    }
    __syncthreads();

    const int wm = (w >> 1) * 32, wn = (w & 1) * 32;
    short8 a[2][4], bfr[2][4];
    #pragma unroll
    for (int kf = 0; kf < 4; ++kf) {
        #pragma unroll
        for (int mf = 0; mf < 2; ++mf)
            a[mf][kf] = *(const short8*)&As[(wm + mf * 16 + lm) * 136 + kf * 32 + lk * 8];
        #pragma unroll
        for (int nf = 0; nf < 2; ++nf)
            bfr[nf][kf] = *(const short8*)&Bs[((kf * 4 + lk) * 66 + wn + nf * 16 + lm) * 8];
    }
    floatx4 acc[2][2] = {};
    #pragma unroll
    for (int kf = 0; kf < 4; ++kf)
        #pragma unroll
        for (int mf = 0; mf < 2; ++mf)
            #pragma unroll
            for (int nf = 0; nf < 2; ++nf)
                acc[mf][nf] = __builtin_amdgcn_mfma_f32_16x16x32_bf16(a[mf][kf], bfr[nf][kf], acc[mf][nf], 0, 0, 0);

    const float* bi = dir ? b_b : b_f;
    #pragma unroll
    for (int mf = 0; mf < 2; ++mf) {
        const int g = gl0 + wm + mf * 16 + lk * 4;
        const float4 bv = *(const float4*)&bi[g];
        #pragma unroll
        for (int nf = 0; nf < 2; ++nf) {
            const int bt = bt0 + wn + nf * 16 + lm;
            const int bb = bt >> 9, t = bt & 511;
            ushort4 o;
            o.x = f_to_bf16(acc[mf][nf][0] + bv.x);
            o.y = f_to_bf16(acc[mf][nf][1] + bv.y);
            o.z = f_to_bf16(acc[mf][nf][2] + bv.z);
            o.w = f_to_bf16(acc[mf][nf][3] + bv.w);
            *(ushort4*)&Xp[((size_t)(dir * B_ + bb) * T_ + t) * G4_ + g] = o;
        }
    }
}

// =====================================================================
// k_lstm: gate-sliced wave layout (round-3 version, verified win).
// =====================================================================
__global__ __launch_bounds__(512) void k_lstm(const uint16_t* __restrict__ Xp,
                                              const uint16_t* __restrict__ WhhB,
                                              uint16_t* __restrict__ hs) {
    __shared__ __align__(16) uint16_t h_sh[2][16 * 136];
    const int dir = blockIdx.y, t0 = blockIdx.x * 16;
    const int tid = threadIdx.x, w = tid >> 6, l = tid & 63;
    const int lm = l & 15, lk = l >> 4;
    const int gcol = w * 16 + lm;
    const int tloc = lk * 4;
    const uint16_t* Wp = WhhB + dir * (G4_ * H_);

    short8 bw[4][4];
    #pragma unroll
    for (int q = 0; q < 4; ++q)
        #pragma unroll
        for (int kf = 0; kf < 4; ++kf)
            bw[q][kf] = *(const short8*)&Wp[(size_t)(q * H_ + gcol) * H_ + kf * 32 + lk * 8];

    for (int i = tid; i < 16 * 136; i += 512) h_sh[0][i] = 0;
    float c[4] = {0.f, 0.f, 0.f, 0.f};

    uint16_t xva[4][4], xvb[4][4];
    {
        const int b0 = dir ? (B_ - 1) : 0;
        const uint16_t* xp = Xp + ((size_t)(dir * B_ + b0) * T_ + t0 + tloc) * G4_;
        #pragma unroll
        for (int r = 0; r < 4; ++r)
            #pragma unroll
            for (int q = 0; q < 4; ++q)
                xva[r][q] = xp[(size_t)r * G4_ + q * H_ + gcol];
    }
    bar_lds();

    auto step = [&](int s, uint16_t (&xc)[4][4], uint16_t (&xn)[4][4], int par) {
        const int b_idx = dir ? (B_ - 1 - s) : s;
        short8 af[4];
        #pragma unroll
        for (int kf = 0; kf < 4; ++kf)
            af[kf] = *(const short8*)&h_sh[par][lm * 136 + kf * 32 + lk * 8];
        floatx4 acc[4] = {};
        #pragma unroll
        for (int q = 0; q < 4; ++q)
            #pragma unroll
            for (int kf = 0; kf < 4; ++kf)
                acc[q] = __builtin_amdgcn_mfma_f32_16x16x32_bf16(af[kf], bw[q][kf], acc[q], 0, 0, 0);
        if (s < B_ - 1) {
            const int bn = dir ? (B_ - 2 - s) : (s + 1);
            const uint16_t* xp = Xp + ((size_t)(dir * B_ + bn) * T_ + t0 + tloc) * G4_;
            #pragma unroll
            for (int r = 0; r < 4; ++r)
                #pragma unroll
                for (int q = 0; q < 4; ++q)
                    xn[r][q] = xp[(size_t)r * G4_ + q * H_ + gcol];
        }
        #pragma unroll
        for (int r = 0; r < 4; ++r) {
            float zi = acc[0][r] + bf16_to_f(xc[r][0]);
            float zf = acc[1][r] + bf16_to_f(xc[r][1]);
            float zg = acc[2][r] + bf16_to_f(xc[r][2]);
            float zo = acc[3][r] + bf16_to_f(xc[r][3]);
            float si = rcpf(1.f + __builtin_amdgcn_exp2f(-LOG2E * zi));
            float sf = rcpf(1.f + __builtin_amdgcn_exp2f(-LOG2E * zf));
            float so = rcpf(1.f + __builtin_amdgcn_exp2f(-LOG2E * zo));
            float tg = 1.f - 2.f * rcpf(1.f + __builtin_amdgcn_exp2f(2.f * LOG2E * zg));
            c[r] = sf * c[r] + si * tg;
            float tc = 1.f - 2.f * rcpf(1.f + __builtin_amdgcn_exp2f(2.f * LOG2E * c[r]));
            float hn = so * tc;
            uint16_t hb = f_to_bf16(hn);
            h_sh[par ^ 1][(tloc + r) * 136 + gcol] = hb;
            hs[((size_t)b_idx * T_ + t0 + tloc + r) * 256 + dir * H_ + gcol] = hb;
        }
        bar_lds();
    };

    for (int s2 = 0; s2 < 16; ++s2) {
        step(2 * s2,     xva, xvb, 0);
        step(2 * s2 + 1, xvb, xva, 1);
    }
}

// =====================================================================
// k_outm: out[b][e][t] fp32 = W_out(128x256) @ hs[b]^T + b_out
// =====================================================================
__global__ __launch_bounds__(256) void k_outm(const uint16_t* __restrict__ WoutB,
                                              const uint16_t* __restrict__ hs,
                                              const float* __restrict__ bout,
                                              float* __restrict__ out) {
    __shared__ __align__(16) uint16_t As[4096], Bs[4096];
    const int b = blockIdx.z, m0 = blockIdx.y * 64, n0 = blockIdx.x * 64;
    const int tid = threadIdx.x, w = tid >> 6, l = tid & 63;
    const int wm = (w >> 1) * 32, wn = (w & 1) * 32;
    const int lm = l & 15, lk = l >> 4;
    const uint16_t* A = WoutB + (size_t)m0 * 256;
    const uint16_t* Bp = hs + ((size_t)b * T_ + n0) * 256;
    floatx4 acc[2][2] = {};
    const uint16_t* gA = A + (size_t)l * 256;
    const uint16_t* gB = Bp + (size_t)l * 256;
    for (int k0 = 0; k0 < 256; k0 += 64) {
        __syncthreads();
        gload16(gA + k0 + (2 * w) * 8,     As + ((2 * w) * 64 + l) * 8);
        gload16(gA + k0 + (2 * w + 1) * 8, As + ((2 * w + 1) * 64 + l) * 8);
        gload16(gB + k0 + (2 * w) * 8,     Bs + ((2 * w) * 64 + l) * 8);
        gload16(gB + k0 + (2 * w + 1) * 8, Bs + ((2 * w + 1) * 64 + l) * 8);
        __syncthreads();
        short8 a[2][2], bfr[2][2];
        #pragma unroll
        for (int kf = 0; kf < 2; ++kf) {
            #pragma unroll
            for (int mf = 0; mf < 2; ++mf)
                a[mf][kf] = *(const short8*)&As[((kf * 4 + lk) * 64 + wm + mf * 16 + lm) * 8];
            #pragma unroll
            for (int nf = 0; nf < 2; ++nf)
                bfr[nf][kf] = *(const short8*)&Bs[((kf * 4 + lk) * 64 + wn + nf * 16 + lm) * 8];
        }
        #pragma unroll
        for (int mf = 0; mf < 2; ++mf)
            #pragma unroll
            for (int nf = 0; nf < 2; ++nf) {
                acc[mf][nf] = __builtin_amdgcn_mfma_f32_16x16x32_bf16(a[mf][0], bfr[nf][0], acc[mf][nf], 0, 0, 0);
                acc[mf][nf] = __builtin_amdgcn_mfma_f32_16x16x32_bf16(a[mf][1], bfr[nf][1], acc[mf][nf], 0, 0, 0);
            }
    }
    #pragma unroll
    for (int mf = 0; mf < 2; ++mf) {
        const int e0 = m0 + wm + mf * 16 + lk * 4;
        const float4 bv = *(const float4*)&bout[e0];
        #pragma unroll
        for (int nf = 0; nf < 2; ++nf) {
            const int t = n0 + wn + nf * 16 + lm;
            out[((size_t)b * H_ + e0 + 0) * T_ + t] = acc[mf][nf][0] + bv.x;
            out[((size_t)b * H_ + e0 + 1) * T_ + t] = acc[mf][nf][1] + bv.y;
            out[((size_t)b * H_ + e0 + 2) * T_ + t] = acc[mf][nf][2] + bv.z;
            out[((size_t)b * H_ + e0 + 3) * T_ + t] = acc[mf][nf][3] + bv.w;
        }
    }
}

// =====================================================================
extern "C" void kernel_launch(void* const* d_in, const int* in_sizes, int n_in,
                              void* d_out, int out_size, void* d_ws, size_t ws_size,
                              hipStream_t stream) {
    const float* x     = (const float*)d_in[0];
    const float* Wfc   = (const float*)d_in[1];
    const float* bfc   = (const float*)d_in[2];
    const float* Wih_f = (const float*)d_in[3];
    const float* Whh_f = (const float*)d_in[4];
    const float* b_f   = (const float*)d_in[5];
    const float* Wih_b = (const float*)d_in[6];
    const float* Whh_b = (const float*)d_in[7];
    const float* b_b   = (const float*)d_in[8];
    const float* Wout  = (const float*)d_in[9];
    const float* bout  = (const float*)d_in[10];
    float* out = (float*)d_out;

    char* ws = (char*)d_ws;
    uint16_t* Xp    = (uint16_t*)(ws);                 // 33,554,432 B
    uint16_t* hsB   = (uint16_t*)(ws + 33554432);      //  8,388,608 B
    float*    Hpart = (float*)   (ws + 41943040);      // 33,554,432 B
    uint16_t* Hcm   = (uint16_t*)(ws + 75497472);      //  4,194,304 B
    uint16_t* Wswz  = (uint16_t*)(ws + 79691776);      //    524,288 B
    uint16_t* WihB  = (uint16_t*)(ws + 80216064);      //    262,144 B
    uint16_t* WhhB  = (uint16_t*)(ws + 80478208);      //    262,144 B
    uint16_t* WoutB = (uint16_t*)(ws + 80740352);      //     65,536 B

    k_cvt_all<<<dim3(544), 256, 0, stream>>>(Wfc, Wih_f, Wih_b, Whh_f, Whh_b, Wout,
                                             Wswz, WihB, WhhB, WoutB);
    k_fc1w <<<dim3(1024),     256, 0, stream>>>(x, Wswz, Hpart);
    k_hsum <<<dim3(16, 128),  256, 0, stream>>>(Hpart, bfc, Hcm);
    k_xproj<<<dim3(256, 16),  256, 0, stream>>>(Hcm, WihB, b_f, b_b, Xp);
    k_lstm <<<dim3(32, 2),    512, 0, stream>>>(Xp, WhhB, hsB);
    k_outm <<<dim3(8, 2, 32), 256, 0, stream>>>(WoutB, hsB, bout, out);
}

// Round 9
// 309.773 us; speedup vs baseline: 1.0732x; 1.0732x over previous
//
#include <hip/hip_runtime.h>
#include <stdint.h>

typedef __attribute__((ext_vector_type(8))) short short8;
typedef __attribute__((ext_vector_type(4))) float floatx4;

// ---------- helpers ----------
__device__ __forceinline__ float bf16_to_f(uint16_t u) {
    union { uint32_t i; float f; } v; v.i = ((uint32_t)u) << 16; return v.f;
}
__device__ __forceinline__ uint16_t f_to_bf16(float f) {
    union { uint32_t i; float f; } v; v.f = f;
    uint32_t u = v.i;
    u += 0x7FFFu + ((u >> 16) & 1u);   // round-to-nearest-even
    return (uint16_t)(u >> 16);
}
__device__ __forceinline__ void gload16(const void* g, void* l) {
    __builtin_amdgcn_global_load_lds(
        (const __attribute__((address_space(1))) void*)g,
        (__attribute__((address_space(3))) void*)l, 16, 0, 0);
}
__device__ __forceinline__ float rcpf(float x) { return __builtin_amdgcn_rcpf(x); }

// LDS-only barrier: waits own LDS ops, does NOT drain vmcnt.
__device__ __forceinline__ void bar_lds() {
    asm volatile("s_waitcnt lgkmcnt(0)" ::: "memory");
    __builtin_amdgcn_s_barrier();
    asm volatile("" ::: "memory");
}

#define B_  32
#define T_  512
#define CF_ 2048
#define H_  128
#define G4_ 512   // 4*H
#define BT_ 16384 // B_*T_
#define LOG2E 1.4426950408889634f

// =====================================================================
// k_cvt_all: weights fp32 -> bf16. W_fc1 PRE-SWIZZLED into exact MFMA
// a-frag order (verified R8): (d,k) -> Wswz[((kc*8+mf)*64+lk*16+lm)*8+e],
// kc=k>>5, lk=(k>>3)&3, e=k&7, mf=d>>4, lm=d&15.
// =====================================================================
__global__ __launch_bounds__(256) void k_cvt_all(
        const float* __restrict__ Wfc, const float* __restrict__ Wih_f,
        const float* __restrict__ Wih_b, const float* __restrict__ Whh_f,
        const float* __restrict__ Whh_b, const float* __restrict__ Wout,
        uint16_t* __restrict__ WswzB, uint16_t* __restrict__ WihB,
        uint16_t* __restrict__ WhhB, uint16_t* __restrict__ WoutB) {
    const int blk = blockIdx.x;
    if (blk < 256) {
        const int i = blk * 1024 + threadIdx.x * 4;
        const int d = i >> 11, k = i & 2047;
        float4 v = *(const float4*)&Wfc[i];
        ushort4 o;
        o.x = f_to_bf16(v.x); o.y = f_to_bf16(v.y);
        o.z = f_to_bf16(v.z); o.w = f_to_bf16(v.w);
        const int kc = k >> 5, lk = (k >> 3) & 3, e = k & 7;
        const int mf = d >> 4, lm = d & 15;
        *(ushort4*)&WswzB[(size_t)(((kc * 8 + mf) * 64 + lk * 16 + lm) * 8 + e)] = o;
        return;
    }
    const float* s; uint16_t* d; int off;
    if (blk < 320)      { s = Wih_f; d = WihB;          off = blk - 256; }
    else if (blk < 384) { s = Wih_b; d = WihB + 65536;  off = blk - 320; }
    else if (blk < 448) { s = Whh_f; d = WhhB;          off = blk - 384; }
    else if (blk < 512) { s = Whh_b; d = WhhB + 65536;  off = blk - 448; }
    else                { s = Wout;  d = WoutB;         off = blk - 512; }
    const int i = off * 1024 + threadIdx.x * 4;
    float4 v = *(const float4*)&s[i];
    ushort4 o;
    o.x = f_to_bf16(v.x); o.y = f_to_bf16(v.y);
    o.z = f_to_bf16(v.z); o.w = f_to_bf16(v.w);
    *(ushort4*)&d[i] = o;
}

// =====================================================================
// k_fc1w2: fc1 GEMM, W AMORTIZED IN LDS + barrier-free K-loop.
// Block = (256-bt tile, kc of K=256). Stage 64 KB W kc-slice (contiguous
// in Wswz) into LDS once -> one __syncthreads -> free-running loop:
// 4 waves x 64 bt, a-frags = contiguous conflict-free ds_read_b128,
// x streamed (64B runs), 32 MFMA / k-step / wave. fp32 partials out.
// Per-CU bytes: 2 blocks x (256K x + 64K W + 128K st) = 896 KB vs R8's
// 3 MB -> predicted ~33 us at the measured ~27 GB/s/CU delivery rate.
// Grid (64, 8) = 512 blocks = 2/CU (LDS 64 KB).
// =====================================================================
__global__ __launch_bounds__(256) void k_fc1w2(const float* __restrict__ x,
                                               const uint16_t* __restrict__ Wswz,
                                               float* __restrict__ Hpart) {
    __shared__ __align__(16) uint16_t Wl[32768];   // 64 KB kc-slice, frag order
    const int tid = threadIdx.x, w = tid >> 6, l = tid & 63;
    const int lm = l & 15, lk = l >> 4;
    const int bt0 = blockIdx.x * 256;              // 64 bt-tiles of 256
    const int kc8 = blockIdx.y;                    // K-split 0..7 (K=256 each)
    const int bb = bt0 >> 9, t0 = bt0 & 511;       // 256 | 512 -> single b
    const int btw = w * 64;                        // wave's bt offset in block

    // one-time W staging: contiguous 64 KB of Wswz -> LDS
    const uint16_t* wsrc = Wswz + (size_t)kc8 * 32768;
    #pragma unroll
    for (int it = 0; it < 16; ++it)
        gload16(wsrc + (size_t)(it * 256 + tid) * 8, Wl + (it * 256 + tid) * 8);
    __syncthreads();   // drains vmcnt -> Wl valid; ONLY barrier in kernel

    const float* xb = x + ((size_t)bb * CF_ + kc8 * 256) * T_ + t0 + btw + lm;

    floatx4 acc[8][4] = {};                        // [mf=d/16][nf=bt/16]
    #pragma unroll 2
    for (int s = 0; s < 8; ++s) {
        const int kk = s * 32;
        // b-frags: 4 nf x 8 k-elems (each load: 4x 64B runs, lanes lm contig)
        short8 bfr[4];
        #pragma unroll
        for (int nf = 0; nf < 4; ++nf) {
            float xv[8];
            #pragma unroll
            for (int j = 0; j < 8; ++j)
                xv[j] = xb[(size_t)(kk + lk * 8 + j) * T_ + nf * 16];
            #pragma unroll
            for (int j = 0; j < 8; ++j)
                bfr[nf][j] = (short)f_to_bf16(xv[j]);
        }
        // a-frags from LDS (contiguous 1 KB/wave -> conflict-free) + MFMA
        #pragma unroll
        for (int mf = 0; mf < 8; ++mf) {
            const short8 a = *(const short8*)&Wl[((s * 8 + mf) * 64 + l) * 8];
            #pragma unroll
            for (int nf = 0; nf < 4; ++nf)
                acc[mf][nf] = __builtin_amdgcn_mfma_f32_16x16x32_bf16(a, bfr[nf], acc[mf][nf], 0, 0, 0);
        }
    }
    // epilogue: fp32 partials, C/D layout row d = mf*16+lk*4+r, col = bt
    float* Hp = Hpart + (size_t)kc8 * H_ * BT_;
    #pragma unroll
    for (int mf = 0; mf < 8; ++mf) {
        const int d0 = mf * 16 + lk * 4;
        #pragma unroll
        for (int nf = 0; nf < 4; ++nf)
            #pragma unroll
            for (int r = 0; r < 4; ++r)
                Hp[(size_t)(d0 + r) * BT_ + bt0 + btw + nf * 16 + lm] = acc[mf][nf][r];
    }
}

// =====================================================================
// k_hsum: Hfc_cm = bf16(sum of 8 Hpart slices + bias), chunk-major
// [c=d>>3][bt][e=d&7] — the B-layout k_xproj's gload_lds needs.
// =====================================================================
__global__ __launch_bounds__(256) void k_hsum(const float* __restrict__ Hpart,
                                              const float* __restrict__ bfc,
                                              uint16_t* __restrict__ Hcm) {
    const int d = blockIdx.y, bt = blockIdx.x * 1024 + threadIdx.x * 4;
    const float b = bfc[d];
    float4 s = *(const float4*)&Hpart[(size_t)d * BT_ + bt];
    #pragma unroll
    for (int kc = 1; kc < 8; ++kc) {
        const float4 v = *(const float4*)&Hpart[(size_t)kc * H_ * BT_ + (size_t)d * BT_ + bt];
        s.x += v.x; s.y += v.y; s.z += v.z; s.w += v.w;
    }
    uint16_t* o = Hcm + ((size_t)(d >> 3) * BT_ + bt) * 8 + (d & 7);
    o[0]  = f_to_bf16(s.x + b);
    o[8]  = f_to_bf16(s.y + b);
    o[16] = f_to_bf16(s.z + b);
    o[24] = f_to_bf16(s.w + b);
}

// =====================================================================
// k_xproj: Xp = Wih_cat[1024 x 128] @ Hfc[128 x 16384]. (verified R7/R8)
// =====================================================================
__global__ __launch_bounds__(256) void k_xproj(const uint16_t* __restrict__ Hcm,
                                               const uint16_t* __restrict__ WihB,
                                               const float* __restrict__ b_f,
                                               const float* __restrict__ b_b,
                                               uint16_t* __restrict__ Xp) {
    __shared__ __align__(16) uint16_t As[64 * 136];
    __shared__ __align__(16) uint16_t Bs[16 * 66 * 8];
    const int bt0 = blockIdx.x * 64, gy = blockIdx.y;
    const int dir = gy >> 3;
    const int gl0 = gy * 64 - dir * 512;
    const int tid = threadIdx.x, w = tid >> 6, l = tid & 63;
    const int lm = l & 15, lk = l >> 4;

    #pragma unroll
    for (int j = 0; j < 4; ++j) {
        const int c = w * 4 + j;
        gload16(Hcm + ((size_t)c * BT_ + bt0 + l) * 8, Bs + (c * 66 + l) * 8);
    }
    {
        const int r = tid >> 2, c4 = tid & 3;
        const uint16_t* src = WihB + (size_t)(gy * 64 + r) * H_ + c4 * 32;
        short8 v0 = *(const short8*)(src);
        short8 v1 = *(const short8*)(src + 8);
        short8 v2 = *(const short8*)(src + 16);
        short8 v3 = *(const short8*)(src + 24);
        uint16_t* dst = &As[r * 136 + c4 * 32];
        *(short8*)(dst)      = v0;
        *(short8*)(dst + 8)  = v1;
        *(short8*)(dst + 16) = v2;
        *(short8*)(dst + 24) = v3;
    }
    __syncthreads();

    const int wm = (w >> 1) * 32, wn = (w & 1) * 32;
    short8 a[2][4], bfr[2][4];
    #pragma unroll
    for (int kf = 0; kf < 4; ++kf) {
        #pragma unroll
        for (int mf = 0; mf < 2; ++mf)
            a[mf][kf] = *(const short8*)&As[(wm + mf * 16 + lm) * 136 + kf * 32 + lk * 8];
        #pragma unroll
        for (int nf = 0; nf < 2; ++nf)
            bfr[nf][kf] = *(const short8*)&Bs[((kf * 4 + lk) * 66 + wn + nf * 16 + lm) * 8];
    }
    floatx4 acc[2][2] = {};
    #pragma unroll
    for (int kf = 0; kf < 4; ++kf)
        #pragma unroll
        for (int mf = 0; mf < 2; ++mf)
            #pragma unroll
            for (int nf = 0; nf < 2; ++nf)
                acc[mf][nf] = __builtin_amdgcn_mfma_f32_16x16x32_bf16(a[mf][kf], bfr[nf][kf], acc[mf][nf], 0, 0, 0);

    const float* bi = dir ? b_b : b_f;
    #pragma unroll
    for (int mf = 0; mf < 2; ++mf) {
        const int g = gl0 + wm + mf * 16 + lk * 4;
        const float4 bv = *(const float4*)&bi[g];
        #pragma unroll
        for (int nf = 0; nf < 2; ++nf) {
            const int bt = bt0 + wn + nf * 16 + lm;
            const int bb = bt >> 9, t = bt & 511;
            ushort4 o;
            o.x = f_to_bf16(acc[mf][nf][0] + bv.x);
            o.y = f_to_bf16(acc[mf][nf][1] + bv.y);
            o.z = f_to_bf16(acc[mf][nf][2] + bv.z);
            o.w = f_to_bf16(acc[mf][nf][3] + bv.w);
            *(ushort4*)&Xp[((size_t)(dir * B_ + bb) * T_ + t) * G4_ + g] = o;
        }
    }
}

// =====================================================================
// k_lstm: gate-sliced wave layout (round-3 version, verified win).
// =====================================================================
__global__ __launch_bounds__(512) void k_lstm(const uint16_t* __restrict__ Xp,
                                              const uint16_t* __restrict__ WhhB,
                                              uint16_t* __restrict__ hs) {
    __shared__ __align__(16) uint16_t h_sh[2][16 * 136];
    const int dir = blockIdx.y, t0 = blockIdx.x * 16;
    const int tid = threadIdx.x, w = tid >> 6, l = tid & 63;
    const int lm = l & 15, lk = l >> 4;
    const int gcol = w * 16 + lm;
    const int tloc = lk * 4;
    const uint16_t* Wp = WhhB + dir * (G4_ * H_);

    short8 bw[4][4];
    #pragma unroll
    for (int q = 0; q < 4; ++q)
        #pragma unroll
        for (int kf = 0; kf < 4; ++kf)
            bw[q][kf] = *(const short8*)&Wp[(size_t)(q * H_ + gcol) * H_ + kf * 32 + lk * 8];

    for (int i = tid; i < 16 * 136; i += 512) h_sh[0][i] = 0;
    float c[4] = {0.f, 0.f, 0.f, 0.f};

    uint16_t xva[4][4], xvb[4][4];
    {
        const int b0 = dir ? (B_ - 1) : 0;
        const uint16_t* xp = Xp + ((size_t)(dir * B_ + b0) * T_ + t0 + tloc) * G4_;
        #pragma unroll
        for (int r = 0; r < 4; ++r)
            #pragma unroll
            for (int q = 0; q < 4; ++q)
                xva[r][q] = xp[(size_t)r * G4_ + q * H_ + gcol];
    }
    bar_lds();

    auto step = [&](int s, uint16_t (&xc)[4][4], uint16_t (&xn)[4][4], int par) {
        const int b_idx = dir ? (B_ - 1 - s) : s;
        short8 af[4];
        #pragma unroll
        for (int kf = 0; kf < 4; ++kf)
            af[kf] = *(const short8*)&h_sh[par][lm * 136 + kf * 32 + lk * 8];
        floatx4 acc[4] = {};
        #pragma unroll
        for (int q = 0; q < 4; ++q)
            #pragma unroll
            for (int kf = 0; kf < 4; ++kf)
                acc[q] = __builtin_amdgcn_mfma_f32_16x16x32_bf16(af[kf], bw[q][kf], acc[q], 0, 0, 0);
        if (s < B_ - 1) {
            const int bn = dir ? (B_ - 2 - s) : (s + 1);
            const uint16_t* xp = Xp + ((size_t)(dir * B_ + bn) * T_ + t0 + tloc) * G4_;
            #pragma unroll
            for (int r = 0; r < 4; ++r)
                #pragma unroll
                for (int q = 0; q < 4; ++q)
                    xn[r][q] = xp[(size_t)r * G4_ + q * H_ + gcol];
        }
        #pragma unroll
        for (int r = 0; r < 4; ++r) {
            float zi = acc[0][r] + bf16_to_f(xc[r][0]);
            float zf = acc[1][r] + bf16_to_f(xc[r][1]);
            float zg = acc[2][r] + bf16_to_f(xc[r][2]);
            float zo = acc[3][r] + bf16_to_f(xc[r][3]);
            float si = rcpf(1.f + __builtin_amdgcn_exp2f(-LOG2E * zi));
            float sf = rcpf(1.f + __builtin_amdgcn_exp2f(-LOG2E * zf));
            float so = rcpf(1.f + __builtin_amdgcn_exp2f(-LOG2E * zo));
            float tg = 1.f - 2.f * rcpf(1.f + __builtin_amdgcn_exp2f(2.f * LOG2E * zg));
            c[r] = sf * c[r] + si * tg;
            float tc = 1.f - 2.f * rcpf(1.f + __builtin_amdgcn_exp2f(2.f * LOG2E * c[r]));
            float hn = so * tc;
            uint16_t hb = f_to_bf16(hn);
            h_sh[par ^ 1][(tloc + r) * 136 + gcol] = hb;
            hs[((size_t)b_idx * T_ + t0 + tloc + r) * 256 + dir * H_ + gcol] = hb;
        }
        bar_lds();
    };

    for (int s2 = 0; s2 < 16; ++s2) {
        step(2 * s2,     xva, xvb, 0);
        step(2 * s2 + 1, xvb, xva, 1);
    }
}

// =====================================================================
// k_outm: out[b][e][t] fp32 = W_out(128x256) @ hs[b]^T + b_out
// =====================================================================
__global__ __launch_bounds__(256) void k_outm(const uint16_t* __restrict__ WoutB,
                                              const uint16_t* __restrict__ hs,
                                              const float* __restrict__ bout,
                                              float* __restrict__ out) {
    __shared__ __align__(16) uint16_t As[4096], Bs[4096];
    const int b = blockIdx.z, m0 = blockIdx.y * 64, n0 = blockIdx.x * 64;
    const int tid = threadIdx.x, w = tid >> 6, l = tid & 63;
    const int wm = (w >> 1) * 32, wn = (w & 1) * 32;
    const int lm = l & 15, lk = l >> 4;
    const uint16_t* A = WoutB + (size_t)m0 * 256;
    const uint16_t* Bp = hs + ((size_t)b * T_ + n0) * 256;
    floatx4 acc[2][2] = {};
    const uint16_t* gA = A + (size_t)l * 256;
    const uint16_t* gB = Bp + (size_t)l * 256;
    for (int k0 = 0; k0 < 256; k0 += 64) {
        __syncthreads();
        gload16(gA + k0 + (2 * w) * 8,     As + ((2 * w) * 64 + l) * 8);
        gload16(gA + k0 + (2 * w + 1) * 8, As + ((2 * w + 1) * 64 + l) * 8);
        gload16(gB + k0 + (2 * w) * 8,     Bs + ((2 * w) * 64 + l) * 8);
        gload16(gB + k0 + (2 * w + 1) * 8, Bs + ((2 * w + 1) * 64 + l) * 8);
        __syncthreads();
        short8 a[2][2], bfr[2][2];
        #pragma unroll
        for (int kf = 0; kf < 2; ++kf) {
            #pragma unroll
            for (int mf = 0; mf < 2; ++mf)
                a[mf][kf] = *(const short8*)&As[((kf * 4 + lk) * 64 + wm + mf * 16 + lm) * 8];
            #pragma unroll
            for (int nf = 0; nf < 2; ++nf)
                bfr[nf][kf] = *(const short8*)&Bs[((kf * 4 + lk) * 64 + wn + nf * 16 + lm) * 8];
        }
        #pragma unroll
        for (int mf = 0; mf < 2; ++mf)
            #pragma unroll
            for (int nf = 0; nf < 2; ++nf) {
                acc[mf][nf] = __builtin_amdgcn_mfma_f32_16x16x32_bf16(a[mf][0], bfr[nf][0], acc[mf][nf], 0, 0, 0);
                acc[mf][nf] = __builtin_amdgcn_mfma_f32_16x16x32_bf16(a[mf][1], bfr[nf][1], acc[mf][nf], 0, 0, 0);
            }
    }
    #pragma unroll
    for (int mf = 0; mf < 2; ++mf) {
        const int e0 = m0 + wm + mf * 16 + lk * 4;
        const float4 bv = *(const float4*)&bout[e0];
        #pragma unroll
        for (int nf = 0; nf < 2; ++nf) {
            const int t = n0 + wn + nf * 16 + lm;
            out[((size_t)b * H_ + e0 + 0) * T_ + t] = acc[mf][nf][0] + bv.x;
            out[((size_t)b * H_ + e0 + 1) * T_ + t] = acc[mf][nf][1] + bv.y;
            out[((size_t)b * H_ + e0 + 2) * T_ + t] = acc[mf][nf][2] + bv.z;
            out[((size_t)b * H_ + e0 + 3) * T_ + t] = acc[mf][nf][3] + bv.w;
        }
    }
}

// =====================================================================
extern "C" void kernel_launch(void* const* d_in, const int* in_sizes, int n_in,
                              void* d_out, int out_size, void* d_ws, size_t ws_size,
                              hipStream_t stream) {
    const float* x     = (const float*)d_in[0];
    const float* Wfc   = (const float*)d_in[1];
    const float* bfc   = (const float*)d_in[2];
    const float* Wih_f = (const float*)d_in[3];
    const float* Whh_f = (const float*)d_in[4];
    const float* b_f   = (const float*)d_in[5];
    const float* Wih_b = (const float*)d_in[6];
    const float* Whh_b = (const float*)d_in[7];
    const float* b_b   = (const float*)d_in[8];
    const float* Wout  = (const float*)d_in[9];
    const float* bout  = (const float*)d_in[10];
    float* out = (float*)d_out;

    char* ws = (char*)d_ws;
    uint16_t* Xp    = (uint16_t*)(ws);                 // 33,554,432 B
    uint16_t* hsB   = (uint16_t*)(ws + 33554432);      //  8,388,608 B
    float*    Hpart = (float*)   (ws + 41943040);      // 67,108,864 B (8 slices)
    uint16_t* Hcm   = (uint16_t*)(ws + 109051904);     //  4,194,304 B
    uint16_t* Wswz  = (uint16_t*)(ws + 113246208);     //    524,288 B
    uint16_t* WihB  = (uint16_t*)(ws + 113770496);     //    262,144 B
    uint16_t* WhhB  = (uint16_t*)(ws + 114032640);     //    262,144 B
    uint16_t* WoutB = (uint16_t*)(ws + 114294784);     //     65,536 B

    k_cvt_all<<<dim3(544), 256, 0, stream>>>(Wfc, Wih_f, Wih_b, Whh_f, Whh_b, Wout,
                                             Wswz, WihB, WhhB, WoutB);
    k_fc1w2<<<dim3(64, 8),    256, 0, stream>>>(x, Wswz, Hpart);
    k_hsum <<<dim3(16, 128),  256, 0, stream>>>(Hpart, bfc, Hcm);
    k_xproj<<<dim3(256, 16),  256, 0, stream>>>(Hcm, WihB, b_f, b_b, Xp);
    k_lstm <<<dim3(32, 2),    512, 0, stream>>>(Xp, WhhB, hsB);
    k_outm <<<dim3(8, 2, 32), 256, 0, stream>>>(WoutB, hsB, bout, out);
}

// Round 10
// 277.755 us; speedup vs baseline: 1.1969x; 1.1153x over previous
//
#include <hip/hip_runtime.h>
#include <stdint.h>

typedef __attribute__((ext_vector_type(8))) short short8;
typedef __attribute__((ext_vector_type(4))) float floatx4;

// ---------- helpers ----------
__device__ __forceinline__ float bf16_to_f(uint16_t u) {
    union { uint32_t i; float f; } v; v.i = ((uint32_t)u) << 16; return v.f;
}
__device__ __forceinline__ uint16_t f_to_bf16(float f) {
    union { uint32_t i; float f; } v; v.f = f;
    uint32_t u = v.i;
    u += 0x7FFFu + ((u >> 16) & 1u);   // round-to-nearest-even
    return (uint16_t)(u >> 16);
}
__device__ __forceinline__ void gload16(const void* g, void* l) {
    __builtin_amdgcn_global_load_lds(
        (const __attribute__((address_space(1))) void*)g,
        (__attribute__((address_space(3))) void*)l, 16, 0, 0);
}
__device__ __forceinline__ float rcpf(float x) { return __builtin_amdgcn_rcpf(x); }

// LDS-only barrier: waits own LDS ops, does NOT drain vmcnt (global loads /
// stores stay in flight across it).
__device__ __forceinline__ void bar_lds() {
    asm volatile("s_waitcnt lgkmcnt(0)" ::: "memory");
    __builtin_amdgcn_s_barrier();
    asm volatile("" ::: "memory");
}

#define B_  32
#define T_  512
#define CF_ 2048
#define H_  128
#define G4_ 512   // 4*H
#define LOG2E 1.4426950408889634f

// =====================================================================
// k_cvt_all: all 6 weight tensors fp32 -> bf16 in ONE launch.
// =====================================================================
__global__ __launch_bounds__(256) void k_cvt_all(
        const float* __restrict__ Wfc, const float* __restrict__ Wih_f,
        const float* __restrict__ Wih_b, const float* __restrict__ Whh_f,
        const float* __restrict__ Whh_b, const float* __restrict__ Wout,
        uint16_t* __restrict__ WfcB, uint16_t* __restrict__ WihB,
        uint16_t* __restrict__ WhhB, uint16_t* __restrict__ WoutB) {
    const int blk = blockIdx.x;
    const float* s; uint16_t* d; int off;
    if (blk < 256)      { s = Wfc;   d = WfcB;          off = blk; }
    else if (blk < 320) { s = Wih_f; d = WihB;          off = blk - 256; }
    else if (blk < 384) { s = Wih_b; d = WihB + 65536;  off = blk - 320; }
    else if (blk < 448) { s = Whh_f; d = WhhB;          off = blk - 384; }
    else if (blk < 512) { s = Whh_b; d = WhhB + 65536;  off = blk - 448; }
    else                { s = Wout;  d = WoutB;         off = blk - 512; }
    const int i = off * 1024 + threadIdx.x * 4;
    float4 v = *(const float4*)&s[i];
    ushort4 o;
    o.x = f_to_bf16(v.x); o.y = f_to_bf16(v.y);
    o.z = f_to_bf16(v.z); o.w = f_to_bf16(v.w);
    *(ushort4*)&d[i] = o;
}

// =====================================================================
// k_fc1x: fused  x-transpose + fc1 + input-projection.
// (round-0 structure, plain __syncthreads — session-best verified config)
// =====================================================================
__global__ __launch_bounds__(512) void k_fc1x(const float* __restrict__ x,
                                              const uint16_t* __restrict__ WfcB,
                                              const float* __restrict__ bfc,
                                              const uint16_t* __restrict__ WihB,
                                              const float* __restrict__ b_f,
                                              const float* __restrict__ b_b,
                                              uint16_t* __restrict__ Xp) {
    __shared__ float tile[64 * 65];                    // [t][cf] fp32
    __shared__ __align__(16) uint16_t As[8192];        // W chunk-major
    __shared__ __align__(16) uint16_t Bs[4224];        // xT chunk-major (stride 66)
    __shared__ __align__(16) uint16_t Hs2[8432];       // Hfc chunk-major (stride 66)

    const int bb = blockIdx.y, n0 = blockIdx.x * 64;
    const int tid = threadIdx.x, w = tid >> 6, l = tid & 63;
    const int lm = l & 15, lk = l >> 4;
    const float* xb = x + (size_t)bb * CF_ * T_;

    // stage-1 mapping (x load / tile write)
    const int t4 = (tid & 15) * 4, cf_r = tid >> 4;    // cf_r in 0..31 (+32)
    // stage-2 mapping (tile read / Bs write)
    const int kk = (tid & 15) * 4, t_r = tid >> 4;     // t_r in 0..31 (+32)

    float4 xv0, xv1;
    {
        const float* p = &xb[(size_t)(0 + cf_r) * T_ + n0 + t4];
        xv0 = *(const float4*)p;
        xv1 = *(const float4*)(p + 32 * T_);
    }

    // ---------------- Phase A ----------------
    const int wmA = (w >> 1) * 32, wnA = (w & 1) * 32;
    floatx4 acc[2][2] = {};
    for (int k0 = 0; k0 < CF_; k0 += 64) {
        __syncthreads();
        // stage1: fp32 transpose tile
        tile[(t4 + 0) * 65 + cf_r] = xv0.x;
        tile[(t4 + 1) * 65 + cf_r] = xv0.y;
        tile[(t4 + 2) * 65 + cf_r] = xv0.z;
        tile[(t4 + 3) * 65 + cf_r] = xv0.w;
        tile[(t4 + 0) * 65 + cf_r + 32] = xv1.x;
        tile[(t4 + 1) * 65 + cf_r + 32] = xv1.y;
        tile[(t4 + 2) * 65 + cf_r + 32] = xv1.z;
        tile[(t4 + 3) * 65 + cf_r + 32] = xv1.w;
        // A staging: wave w stages chunk w (k-offset w*8), rows l and 64+l
        gload16(WfcB + (size_t)l * CF_ + k0 + w * 8,        As + (w * 128 + l) * 8);
        gload16(WfcB + (size_t)(64 + l) * CF_ + k0 + w * 8, As + (w * 128 + 64 + l) * 8);
        __syncthreads();
        // prefetch next x block
        if (k0 + 64 < CF_) {
            const float* p = &xb[(size_t)(k0 + 64 + cf_r) * T_ + n0 + t4];
            xv0 = *(const float4*)p;
            xv1 = *(const float4*)(p + 32 * T_);
        }
        // stage2: tile -> bf16 chunk-major Bs
        #pragma unroll
        for (int pass = 0; pass < 2; ++pass) {
            const int tr = t_r + pass * 32;
            ushort4 o;
            o.x = f_to_bf16(tile[tr * 65 + kk + 0]);
            o.y = f_to_bf16(tile[tr * 65 + kk + 1]);
            o.z = f_to_bf16(tile[tr * 65 + kk + 2]);
            o.w = f_to_bf16(tile[tr * 65 + kk + 3]);
            *(ushort4*)&Bs[((kk >> 3) * 66 + tr) * 8 + (kk & 7)] = o;
        }
        __syncthreads();
        // frags + MFMA
        short8 a[2][2], bfr[2][2];
        #pragma unroll
        for (int kf = 0; kf < 2; ++kf) {
            #pragma unroll
            for (int mf = 0; mf < 2; ++mf)
                a[mf][kf] = *(const short8*)&As[((kf * 4 + lk) * 128 + wmA + mf * 16 + lm) * 8];
            #pragma unroll
            for (int nf = 0; nf < 2; ++nf)
                bfr[nf][kf] = *(const short8*)&Bs[((kf * 4 + lk) * 66 + wnA + nf * 16 + lm) * 8];
        }
        #pragma unroll
        for (int mf = 0; mf < 2; ++mf)
            #pragma unroll
            for (int nf = 0; nf < 2; ++nf) {
                acc[mf][nf] = __builtin_amdgcn_mfma_f32_16x16x32_bf16(a[mf][0], bfr[nf][0], acc[mf][nf], 0, 0, 0);
                acc[mf][nf] = __builtin_amdgcn_mfma_f32_16x16x32_bf16(a[mf][1], bfr[nf][1], acc[mf][nf], 0, 0, 0);
            }
    }
    __syncthreads();
    // epilogue A: bias + bf16 -> Hs2 chunk-major (stride 66)
    #pragma unroll
    for (int mf = 0; mf < 2; ++mf) {
        const int d0 = wmA + mf * 16 + lk * 4;
        const float4 bv = *(const float4*)&bfc[d0];
        const int c = ((wmA + mf * 16) >> 3) + (lk >> 1);
        #pragma unroll
        for (int nf = 0; nf < 2; ++nf) {
            const int t = wnA + nf * 16 + lm;
            ushort4 o;
            o.x = f_to_bf16(acc[mf][nf][0] + bv.x);
            o.y = f_to_bf16(acc[mf][nf][1] + bv.y);
            o.z = f_to_bf16(acc[mf][nf][2] + bv.z);
            o.w = f_to_bf16(acc[mf][nf][3] + bv.w);
            *(ushort4*)&Hs2[(c * 66 + t) * 8 + (lk & 1) * 4] = o;
        }
    }
    __syncthreads();

    // ---------------- Phase B ----------------
    const int dirw = w >> 2;
    const int db   = dirw * B_ + bb;
    const uint16_t* Wp = WihB + (size_t)dirw * (G4_ * H_);
    const float* bi = dirw ? b_b : b_f;
    #pragma unroll
    for (int it = 0; it < 2; ++it) {
        const int gbase = (w & 3) * 64 + it * 256;
        short8 aw[4][4];
        #pragma unroll
        for (int mf = 0; mf < 4; ++mf)
            #pragma unroll
            for (int kf = 0; kf < 4; ++kf)
                aw[mf][kf] = *(const short8*)&Wp[(size_t)(gbase + mf * 16 + lm) * H_ + kf * 32 + lk * 8];
        floatx4 acc2[4][4] = {};
        #pragma unroll
        for (int nf = 0; nf < 4; ++nf) {
            short8 bbf[4];
            #pragma unroll
            for (int kf = 0; kf < 4; ++kf)
                bbf[kf] = *(const short8*)&Hs2[((kf * 4 + lk) * 66 + nf * 16 + lm) * 8];
            #pragma unroll
            for (int mf = 0; mf < 4; ++mf)
                #pragma unroll
                for (int kf = 0; kf < 4; ++kf)
                    acc2[mf][nf] = __builtin_amdgcn_mfma_f32_16x16x32_bf16(aw[mf][kf], bbf[kf], acc2[mf][nf], 0, 0, 0);
        }
        #pragma unroll
        for (int mf = 0; mf < 4; ++mf) {
            const int g0 = gbase + mf * 16 + lk * 4;
            const float4 bv = *(const float4*)&bi[g0];
            #pragma unroll
            for (int nf = 0; nf < 4; ++nf) {
                const int t = n0 + nf * 16 + lm;
                ushort4 o;
                o.x = f_to_bf16(acc2[mf][nf][0] + bv.x);
                o.y = f_to_bf16(acc2[mf][nf][1] + bv.y);
                o.z = f_to_bf16(acc2[mf][nf][2] + bv.z);
                o.w = f_to_bf16(acc2[mf][nf][3] + bv.w);
                *(ushort4*)&Xp[((size_t)db * T_ + t) * G4_ + g0] = o;
            }
        }
    }
}

// =====================================================================
// k_lstm: gate-sliced wave layout (verified win, round 3).
// Wave w computes n-frags at g = q*128 + w*16 (q = gate index 0..3), so
// each lane's accumulators hold ALL FOUR gates for its (t, hh) —
// activation fully in-register, one barrier per step, Xp prefetched.
// =====================================================================
__global__ __launch_bounds__(512) void k_lstm(const uint16_t* __restrict__ Xp,
                                              const uint16_t* __restrict__ WhhB,
                                              uint16_t* __restrict__ hs) {
    __shared__ __align__(16) uint16_t h_sh[2][16 * 136];
    const int dir = blockIdx.y, t0 = blockIdx.x * 16;
    const int tid = threadIdx.x, w = tid >> 6, l = tid & 63;
    const int lm = l & 15, lk = l >> 4;
    const int gcol = w * 16 + lm;          // h-column this lane owns
    const int tloc = lk * 4;               // t-row base this lane owns
    const uint16_t* Wp = WhhB + dir * (G4_ * H_);

    // B-frags: bw[q][kf] = Whh rows g = q*128 + gcol, k-chunk kf
    short8 bw[4][4];
    #pragma unroll
    for (int q = 0; q < 4; ++q)
        #pragma unroll
        for (int kf = 0; kf < 4; ++kf)
            bw[q][kf] = *(const short8*)&Wp[(size_t)(q * H_ + gcol) * H_ + kf * 32 + lk * 8];

    for (int i = tid; i < 16 * 136; i += 512) h_sh[0][i] = 0;
    float c[4] = {0.f, 0.f, 0.f, 0.f};

    uint16_t xva[4][4], xvb[4][4];
    // preload step 0 gate-inputs
    {
        const int b0 = dir ? (B_ - 1) : 0;
        const uint16_t* xp = Xp + ((size_t)(dir * B_ + b0) * T_ + t0 + tloc) * G4_;
        #pragma unroll
        for (int r = 0; r < 4; ++r)
            #pragma unroll
            for (int q = 0; q < 4; ++q)
                xva[r][q] = xp[(size_t)r * G4_ + q * H_ + gcol];
    }
    bar_lds();   // h_sh[0] zeros visible

    auto step = [&](int s, uint16_t (&xc)[4][4], uint16_t (&xn)[4][4], int par) {
        const int b_idx = dir ? (B_ - 1 - s) : s;
        // A-frags from h(prev)
        short8 af[4];
        #pragma unroll
        for (int kf = 0; kf < 4; ++kf)
            af[kf] = *(const short8*)&h_sh[par][lm * 136 + kf * 32 + lk * 8];
        floatx4 acc[4] = {};
        #pragma unroll
        for (int q = 0; q < 4; ++q)
            #pragma unroll
            for (int kf = 0; kf < 4; ++kf)
                acc[q] = __builtin_amdgcn_mfma_f32_16x16x32_bf16(af[kf], bw[q][kf], acc[q], 0, 0, 0);
        // prefetch next step's gate-inputs (hidden under MFMA + activation)
        if (s < B_ - 1) {
            const int bn = dir ? (B_ - 2 - s) : (s + 1);
            const uint16_t* xp = Xp + ((size_t)(dir * B_ + bn) * T_ + t0 + tloc) * G4_;
            #pragma unroll
            for (int r = 0; r < 4; ++r)
                #pragma unroll
                for (int q = 0; q < 4; ++q)
                    xn[r][q] = xp[(size_t)r * G4_ + q * H_ + gcol];
        }
        // in-register activation; write h to h_sh[par^1] + global hs
        #pragma unroll
        for (int r = 0; r < 4; ++r) {
            float zi = acc[0][r] + bf16_to_f(xc[r][0]);
            float zf = acc[1][r] + bf16_to_f(xc[r][1]);
            float zg = acc[2][r] + bf16_to_f(xc[r][2]);
            float zo = acc[3][r] + bf16_to_f(xc[r][3]);
            float si = rcpf(1.f + __builtin_amdgcn_exp2f(-LOG2E * zi));
            float sf = rcpf(1.f + __builtin_amdgcn_exp2f(-LOG2E * zf));
            float so = rcpf(1.f + __builtin_amdgcn_exp2f(-LOG2E * zo));
            float tg = 1.f - 2.f * rcpf(1.f + __builtin_amdgcn_exp2f(2.f * LOG2E * zg));
            c[r] = sf * c[r] + si * tg;
            float tc = 1.f - 2.f * rcpf(1.f + __builtin_amdgcn_exp2f(2.f * LOG2E * c[r]));
            float hn = so * tc;
            uint16_t hb = f_to_bf16(hn);
            h_sh[par ^ 1][(tloc + r) * 136 + gcol] = hb;
            hs[((size_t)b_idx * T_ + t0 + tloc + r) * 256 + dir * H_ + gcol] = hb;
        }
        bar_lds();   // ONE barrier per step: h(next) visible, prev reads done
    };

    for (int s2 = 0; s2 < 16; ++s2) {
        step(2 * s2,     xva, xvb, 0);
        step(2 * s2 + 1, xvb, xva, 1);
    }
}

// =====================================================================
// k_outm: out[b][e][t] fp32 = W_out(128x256) @ hs[b]^T + b_out
// 64x64 tiles, BK=64, grid (8, 2, 32)
// =====================================================================
__global__ __launch_bounds__(256) void k_outm(const uint16_t* __restrict__ WoutB,
                                              const uint16_t* __restrict__ hs,
                                              const float* __restrict__ bout,
                                              float* __restrict__ out) {
    __shared__ __align__(16) uint16_t As[4096], Bs[4096];
    const int b = blockIdx.z, m0 = blockIdx.y * 64, n0 = blockIdx.x * 64;
    const int tid = threadIdx.x, w = tid >> 6, l = tid & 63;
    const int wm = (w >> 1) * 32, wn = (w & 1) * 32;
    const int lm = l & 15, lk = l >> 4;
    const uint16_t* A = WoutB + (size_t)m0 * 256;
    const uint16_t* Bp = hs + ((size_t)b * T_ + n0) * 256;
    floatx4 acc[2][2] = {};
    const uint16_t* gA = A + (size_t)l * 256;
    const uint16_t* gB = Bp + (size_t)l * 256;
    for (int k0 = 0; k0 < 256; k0 += 64) {
        __syncthreads();
        gload16(gA + k0 + (2 * w) * 8,     As + ((2 * w) * 64 + l) * 8);
        gload16(gA + k0 + (2 * w + 1) * 8, As + ((2 * w + 1) * 64 + l) * 8);
        gload16(gB + k0 + (2 * w) * 8,     Bs + ((2 * w) * 64 + l) * 8);
        gload16(gB + k0 + (2 * w + 1) * 8, Bs + ((2 * w + 1) * 64 + l) * 8);
        __syncthreads();
        short8 a[2][2], bfr[2][2];
        #pragma unroll
        for (int kf = 0; kf < 2; ++kf) {
            #pragma unroll
            for (int mf = 0; mf < 2; ++mf)
                a[mf][kf] = *(const short8*)&As[((kf * 4 + lk) * 64 + wm + mf * 16 + lm) * 8];
            #pragma unroll
            for (int nf = 0; nf < 2; ++nf)
                bfr[nf][kf] = *(const short8*)&Bs[((kf * 4 + lk) * 64 + wn + nf * 16 + lm) * 8];
        }
        #pragma unroll
        for (int mf = 0; mf < 2; ++mf)
            #pragma unroll
            for (int nf = 0; nf < 2; ++nf) {
                acc[mf][nf] = __builtin_amdgcn_mfma_f32_16x16x32_bf16(a[mf][0], bfr[nf][0], acc[mf][nf], 0, 0, 0);
                acc[mf][nf] = __builtin_amdgcn_mfma_f32_16x16x32_bf16(a[mf][1], bfr[nf][1], acc[mf][nf], 0, 0, 0);
            }
    }
    #pragma unroll
    for (int mf = 0; mf < 2; ++mf) {
        const int e0 = m0 + wm + mf * 16 + lk * 4;
        const float4 bv = *(const float4*)&bout[e0];
        #pragma unroll
        for (int nf = 0; nf < 2; ++nf) {
            const int t = n0 + wn + nf * 16 + lm;
            out[((size_t)b * H_ + e0 + 0) * T_ + t] = acc[mf][nf][0] + bv.x;
            out[((size_t)b * H_ + e0 + 1) * T_ + t] = acc[mf][nf][1] + bv.y;
            out[((size_t)b * H_ + e0 + 2) * T_ + t] = acc[mf][nf][2] + bv.z;
            out[((size_t)b * H_ + e0 + 3) * T_ + t] = acc[mf][nf][3] + bv.w;
        }
    }
}

// =====================================================================
extern "C" void kernel_launch(void* const* d_in, const int* in_sizes, int n_in,
                              void* d_out, int out_size, void* d_ws, size_t ws_size,
                              hipStream_t stream) {
    const float* x     = (const float*)d_in[0];
    const float* Wfc   = (const float*)d_in[1];
    const float* bfc   = (const float*)d_in[2];
    const float* Wih_f = (const float*)d_in[3];
    const float* Whh_f = (const float*)d_in[4];
    const float* b_f   = (const float*)d_in[5];
    const float* Wih_b = (const float*)d_in[6];
    const float* Whh_b = (const float*)d_in[7];
    const float* b_b   = (const float*)d_in[8];
    const float* Wout  = (const float*)d_in[9];
    const float* bout  = (const float*)d_in[10];
    float* out = (float*)d_out;

    char* ws = (char*)d_ws;
    uint16_t* Xp    = (uint16_t*)(ws);                 // 33,554,432 B
    uint16_t* hsB   = (uint16_t*)(ws + 33554432);      //  8,388,608 B
    uint16_t* WfcB  = (uint16_t*)(ws + 41943040);      //    524,288 B
    uint16_t* WihB  = (uint16_t*)(ws + 42467328);      //    262,144 B
    uint16_t* WhhB  = (uint16_t*)(ws + 42729472);      //    262,144 B
    uint16_t* WoutB = (uint16_t*)(ws + 42991616);      //     65,536 B

    k_cvt_all<<<dim3(544), 256, 0, stream>>>(Wfc, Wih_f, Wih_b, Whh_f, Whh_b, Wout,
                                             WfcB, WihB, WhhB, WoutB);
    k_fc1x <<<dim3(8, 32),   512, 0, stream>>>(x, WfcB, bfc, WihB, b_f, b_b, Xp);
    k_lstm <<<dim3(32, 2),   512, 0, stream>>>(Xp, WhhB, hsB);
    k_outm <<<dim3(8, 2, 32), 256, 0, stream>>>(WoutB, hsB, bout, out);
}